// Round 3
// baseline (1082.561 us; speedup 1.0000x reference)
//
#include <hip/hip_runtime.h>

#define NN 100000
#define NE 800000
#define HID 256

typedef __attribute__((ext_vector_type(8))) short bf16x8;
typedef __attribute__((ext_vector_type(4))) float f32x4;
typedef __attribute__((ext_vector_type(2))) float f32x2;

__device__ __forceinline__ float bf2f(unsigned short u) {
    return __uint_as_float(((unsigned)u) << 16);
}
__device__ __forceinline__ unsigned short f2bf(float f) {
    unsigned u = __float_as_uint(f);
    u += 0x7fffu + ((u >> 16) & 1u);   // RNE
    return (unsigned short)(u >> 16);
}

// ---------- dtype probes (device-side, graph-safe) ----------
// flags[0] = 1 if float arrays are f32 (else bf16)
// flags[1] = 1 if edge_index is int64 (else int32)
__global__ void probe_kernel(const void* W1, const void* edge, int* flags) {
    __shared__ int s_f32, s_odd;
    if (threadIdx.x == 0) { s_f32 = 0; s_odd = 0; }
    __syncthreads();
    const unsigned short* wu = (const unsigned short*)W1;
    for (int i = threadIdx.x; i < 2048; i += 256) {
        float v = bf2f(wu[i]);
        if (!(fabsf(v) <= 1.0f)) atomicOr(&s_f32, 1);  // glorot |w|<=0.125; junk exceeds 1
    }
    const int* ei = (const int*)edge;
    for (int i = threadIdx.x; i < 512; i += 256) {
        if (ei[2 * i + 1] != 0) atomicOr(&s_odd, 1);   // int64 high words are all 0
    }
    __syncthreads();
    if (threadIdx.x == 0) { flags[0] = s_f32; flags[1] = s_odd ? 0 : 1; }
}

__device__ __forceinline__ int get_edge(const void* edge, int e64, long long idx) {
    return e64 ? (int)((const long long*)edge)[idx] : ((const int*)edge)[idx];
}
__device__ __forceinline__ float get_f(const void* p, int f32, size_t idx) {
    return f32 ? ((const float*)p)[idx] : bf2f(((const unsigned short*)p)[idx]);
}

// ---------- CSR build ----------
__global__ void zero_kernel(int* deg, int n) {
    int i = blockIdx.x * 256 + threadIdx.x;
    if (i < n) deg[i] = 0;
}
__global__ void count_kernel(const void* __restrict__ edge, const int* __restrict__ flags,
                             int* __restrict__ deg, int e) {
    int i = blockIdx.x * 256 + threadIdx.x;
    if (i < e) atomicAdd(&deg[get_edge(edge, flags[1], (long long)NE + i)], 1);
}
__global__ void dinv_kernel(const int* __restrict__ deg, float* __restrict__ dinv, int n) {
    int i = blockIdx.x * 256 + threadIdx.x;
    if (i < n) dinv[i] = 1.0f / sqrtf((float)(deg[i] + 1));
}
__global__ void scanA_kernel(const int* __restrict__ deg, int* __restrict__ rp,
                             int* __restrict__ bsums, int n) {
    __shared__ int sd[256];
    int tid = threadIdx.x;
    int base = blockIdx.x * 1024 + tid * 4;
    int v[4]; int ts = 0;
    for (int j = 0; j < 4; ++j) { v[j] = (base + j < n) ? deg[base + j] : 0; ts += v[j]; }
    sd[tid] = ts;
    __syncthreads();
    for (int off = 1; off < 256; off <<= 1) {
        int t = (tid >= off) ? sd[tid - off] : 0;
        __syncthreads();
        sd[tid] += t;
        __syncthreads();
    }
    int run = sd[tid] - ts;
    for (int j = 0; j < 4; ++j) {
        if (base + j < n) rp[base + j] = run;
        run += v[j];
    }
    if (tid == 255) bsums[blockIdx.x] = sd[255];
}
__global__ void scanB_kernel(int* bsums, int nb) {
    __shared__ int sd[128];
    int tid = threadIdx.x;
    int v = (tid < nb) ? bsums[tid] : 0;
    sd[tid] = v;
    __syncthreads();
    for (int off = 1; off < 128; off <<= 1) {
        int t = (tid >= off) ? sd[tid - off] : 0;
        __syncthreads();
        sd[tid] += t;
        __syncthreads();
    }
    if (tid < nb) bsums[tid] = sd[tid] - v;
}
__global__ void scanC_kernel(int* __restrict__ rp, const int* __restrict__ bsums, int n) {
    int base = blockIdx.x * 1024 + threadIdx.x * 4;
    int off = bsums[blockIdx.x];
    for (int j = 0; j < 4; ++j)
        if (base + j < n) rp[base + j] += off;
}
// uses deg as a countdown cursor (destroys it; dinv already extracted)
__global__ void fill_kernel(const void* __restrict__ edge, const int* __restrict__ flags,
                            const int* __restrict__ rp, int* __restrict__ deg,
                            int* __restrict__ csr, int e) {
    int i = blockIdx.x * 256 + threadIdx.x;
    if (i >= e) return;
    int e64 = flags[1];
    int s = get_edge(edge, e64, i);
    int d = get_edge(edge, e64, (long long)NE + i);
    int slot = atomicAdd(&deg[d], -1) - 1;
    csr[rp[d] + slot] = s;
}

// ---------- weight transpose + hi/lo split: W[k,256] -> Wh/Wl[n,K] ----------
__global__ void transpose_kernel(const void* __restrict__ W, const int* __restrict__ flags,
                                 unsigned short* __restrict__ Wh, unsigned short* __restrict__ Wl,
                                 int K) {
    int k = blockIdx.x, n = threadIdx.x;
    float v = get_f(W, flags[0], (size_t)k * 256 + n);
    unsigned short h = f2bf(v);
    Wh[n * K + k] = h;
    Wl[n * K + k] = f2bf(v - bf2f(h));
}

// ---------- GEMM: H[M,128](f32) = A[M,K] @ W[:, col0:col0+128], hi/lo split ----------
#define BM 128
#define BK 32
#define LDA 40

__global__ __launch_bounds__(256) void gemm_kernel(
    const void* __restrict__ A0p, int A0off, int A0s,
    const void* __restrict__ A1p, int A1off, int A1s,
    const int* __restrict__ flags,
    const unsigned short* __restrict__ Wh, const unsigned short* __restrict__ Wl,
    int col0, float* __restrict__ H, int M, int K) {
    __shared__ __align__(16) short Ah[BM * LDA];
    __shared__ __align__(16) short Al[BM * LDA];
    __shared__ __align__(16) short Bh[128 * LDA];
    __shared__ __align__(16) short Bl[128 * LDA];

    int tid = threadIdx.x;
    int lane = tid & 63;
    int wave = tid >> 6;
    int wm = wave >> 1, wn = wave & 1;
    int row0 = blockIdx.x * BM;
    int f32 = flags[0];

    f32x4 acc[4][4];
    for (int mt = 0; mt < 4; ++mt)
        for (int nt = 0; nt < 4; ++nt)
            acc[mt][nt] = (f32x4){0.f, 0.f, 0.f, 0.f};

    for (int k0 = 0; k0 < K; k0 += BK) {
        // ---- stage A (hi/lo) ----
        for (int s = tid; s < 512; s += 256) {
            int r = s >> 2, q = s & 3;
            int gr = row0 + r;
            int k = k0 + q * 8;
            int lds = r * LDA + q * 8;
            if (gr < M) {
                size_t eidx = (k < 128)
                    ? (size_t)A0off + (size_t)gr * A0s + k
                    : (size_t)A1off + (size_t)gr * A1s + (k - 128);
                const void* pl = (k < 128) ? A0p : A1p;
                if (f32) {
                    const float* bp = (const float*)pl + eidx;
                    float4 v0 = *(const float4*)bp;
                    float4 v1 = *(const float4*)(bp + 4);
                    float vv[8] = {v0.x, v0.y, v0.z, v0.w, v1.x, v1.y, v1.z, v1.w};
                    for (int j = 0; j < 8; ++j) {
                        unsigned short h = f2bf(vv[j]);
                        Ah[lds + j] = (short)h;
                        Al[lds + j] = (short)f2bf(vv[j] - bf2f(h));
                    }
                } else {
                    const unsigned short* bp = (const unsigned short*)pl + eidx;
                    uint4 v = *(const uint4*)bp;
                    *(uint4*)&Ah[lds] = v;
                    *(uint4*)&Al[lds] = make_uint4(0, 0, 0, 0);
                }
            } else {
                *(uint4*)&Ah[lds] = make_uint4(0, 0, 0, 0);
                *(uint4*)&Al[lds] = make_uint4(0, 0, 0, 0);
            }
        }
        // ---- stage B (hi/lo, already bf16 in ws) ----
        for (int s = tid; s < 512; s += 256) {
            int r = s >> 2, q = s & 3;
            size_t gi = (size_t)(col0 + r) * K + k0 + q * 8;
            int lds = r * LDA + q * 8;
            *(uint4*)&Bh[lds] = *(const uint4*)(Wh + gi);
            *(uint4*)&Bl[lds] = *(const uint4*)(Wl + gi);
        }
        __syncthreads();

        int kq = (lane >> 4) * 8;
        bf16x8 ah[4], al[4], bh[4], bl[4];
        for (int t = 0; t < 4; ++t) {
            int ar = (wm * 64 + t * 16 + (lane & 15)) * LDA + kq;
            int br = (wn * 64 + t * 16 + (lane & 15)) * LDA + kq;
            ah[t] = *(const bf16x8*)&Ah[ar];
            al[t] = *(const bf16x8*)&Al[ar];
            bh[t] = *(const bf16x8*)&Bh[br];
            bl[t] = *(const bf16x8*)&Bl[br];
        }
        for (int mt = 0; mt < 4; ++mt)
            for (int nt = 0; nt < 4; ++nt) {
                acc[mt][nt] = __builtin_amdgcn_mfma_f32_16x16x32_bf16(ah[mt], bh[nt], acc[mt][nt], 0, 0, 0);
                acc[mt][nt] = __builtin_amdgcn_mfma_f32_16x16x32_bf16(ah[mt], bl[nt], acc[mt][nt], 0, 0, 0);
                acc[mt][nt] = __builtin_amdgcn_mfma_f32_16x16x32_bf16(al[mt], bh[nt], acc[mt][nt], 0, 0, 0);
            }
        __syncthreads();
    }

    // epilogue: C/D layout col=lane&15, row=(lane>>4)*4+i  (H compact [M,128] f32)
    for (int mt = 0; mt < 4; ++mt)
        for (int nt = 0; nt < 4; ++nt) {
            int col = wn * 64 + nt * 16 + (lane & 15);
            int rbase = row0 + wm * 64 + mt * 16 + ((lane >> 4) << 2);
            for (int i = 0; i < 4; ++i) {
                int r = rbase + i;
                if (r < M) H[(size_t)r * 128 + col] = acc[mt][nt][i];
            }
        }
}

// ---------- aggregation: one wave per node over a 128-col half ----------
__global__ __launch_bounds__(256) void agg_kernel(
    const float* __restrict__ H, const int* __restrict__ csr,
    const int* __restrict__ rp, const float* __restrict__ dinv,
    const void* __restrict__ bias, const int* __restrict__ flags,
    void* __restrict__ outp, int coff, int ostride,
    int relu, int n) {
    int wave = threadIdx.x >> 6;
    int lane = threadIdx.x & 63;
    int node = blockIdx.x * 4 + wave;
    if (node >= n) return;
    int c = lane * 2;
    int f32 = flags[0];

    f32x2 acc = (f32x2){0.f, 0.f};
    int beg = rp[node];
    int cnt = ((node == n - 1) ? NE : rp[node + 1]) - beg;
    for (int i = 0; i < cnt; ++i) {
        int s = csr[beg + i];
        float w = dinv[s];
        f32x2 hv = *(const f32x2*)(H + (size_t)s * 128 + c);
        acc += hv * w;
    }
    float dn = dinv[node];
    f32x2 hn = *(const f32x2*)(H + (size_t)node * 128 + c);
    acc = acc * dn + hn * (dn * dn);

    acc[0] += get_f(bias, f32, (size_t)(coff + c));
    acc[1] += get_f(bias, f32, (size_t)(coff + c + 1));
    if (relu) {
        acc[0] = fmaxf(acc[0], 0.f);
        acc[1] = fmaxf(acc[1], 0.f);
    }

    size_t o = (size_t)coff + (size_t)node * ostride + c;
    if (f32) {
        *(f32x2*)((float*)outp + o) = acc;
    } else {
        ushort2 u;
        u.x = f2bf(acc[0]);
        u.y = f2bf(acc[1]);
        *(ushort2*)((unsigned short*)outp + o) = u;
    }
}

// ---------- launch ----------
extern "C" void kernel_launch(void* const* d_in, const int* in_sizes, int n_in,
                              void* d_out, int out_size, void* d_ws, size_t ws_size,
                              hipStream_t stream) {
    const void* x    = d_in[0];
    const void* edge = d_in[1];
    const void* W1   = d_in[2];
    const void* b1   = d_in[3];
    const void* W2   = d_in[4];
    const void* b2   = d_in[5];
    const void* W3   = d_in[6];
    const void* b3   = d_in[7];
    void* xbuf = d_in[0];   // clobberable: restored before every launch

    const int N = NN, E = NE;

    char* w = (char*)d_ws;
    auto carve = [&](size_t bytes) -> void* {
        void* p = (void*)w;
        w += (bytes + 255) & ~(size_t)255;
        return p;
    };
    int*   flags = (int*)carve(256);
    int*   deg   = (int*)carve((size_t)N * 4);
    float* dinv  = (float*)carve((size_t)N * 4);
    int*   rp    = (int*)carve((size_t)N * 4);
    int*   bsums = (int*)carve(512);
    int*   csr   = (int*)carve((size_t)E * 4);
    unsigned short* Wh = (unsigned short*)carve((size_t)256 * 256 * 2);
    unsigned short* Wl = (unsigned short*)carve((size_t)256 * 256 * 2);
    float* H = (float*)carve((size_t)N * 128 * 4);   // 51.2 MB; total ~55.9 MB

    int gN = (N + 255) / 256;
    int gE = (E + 255) / 256;
    int nb = (N + 1023) / 1024;
    dim3 ggemm((N + BM - 1) / BM, 1);   // 782
    int gagg = (N + 3) / 4;             // 25000

    probe_kernel<<<1, 256, 0, stream>>>(W1, edge, flags);
    zero_kernel<<<gN, 256, 0, stream>>>(deg, N);
    count_kernel<<<gE, 256, 0, stream>>>(edge, flags, deg, E);
    dinv_kernel<<<gN, 256, 0, stream>>>(deg, dinv, N);
    scanA_kernel<<<nb, 256, 0, stream>>>(deg, rp, bsums, N);
    scanB_kernel<<<1, 128, 0, stream>>>(bsums, nb);
    scanC_kernel<<<nb, 256, 0, stream>>>(rp, bsums, N);
    fill_kernel<<<gE, 256, 0, stream>>>(edge, flags, rp, deg, csr, E);

    // ---- layer 1: A = x [N,128] ----
    transpose_kernel<<<128, 256, 0, stream>>>(W1, flags, Wh, Wl, 128);
    gemm_kernel<<<ggemm, 256, 0, stream>>>(x, 0, 128, x, 0, 128, flags, Wh, Wl, 0, H, N, 128);
    agg_kernel<<<gagg, 256, 0, stream>>>(H, csr, rp, dinv, b1, flags, d_out, 0, 256, 1, N);
    gemm_kernel<<<ggemm, 256, 0, stream>>>(x, 0, 128, x, 0, 128, flags, Wh, Wl, 128, H, N, 128);
    agg_kernel<<<gagg, 256, 0, stream>>>(H, csr, rp, dinv, b1, flags, d_out, 128, 256, 1, N);

    // ---- layer 2: A = d_out [N,256]; x is dead -> xbuf becomes the col 0:128 stash ----
    transpose_kernel<<<256, 256, 0, stream>>>(W2, flags, Wh, Wl, 256);
    gemm_kernel<<<ggemm, 256, 0, stream>>>(d_out, 0, 256, d_out, 128, 256, flags, Wh, Wl, 0, H, N, 256);
    agg_kernel<<<gagg, 256, 0, stream>>>(H, csr, rp, dinv, b2, flags, xbuf, 0, 128, 1, N);
    gemm_kernel<<<ggemm, 256, 0, stream>>>(d_out, 0, 256, d_out, 128, 256, flags, Wh, Wl, 128, H, N, 256);
    agg_kernel<<<gagg, 256, 0, stream>>>(H, csr, rp, dinv, b2, flags, d_out, 128, 256, 1, N);

    // ---- layer 3: A = { xbuf[:,0:128], d_out[:,128:256] }; final out -> d_out ----
    transpose_kernel<<<256, 256, 0, stream>>>(W3, flags, Wh, Wl, 256);
    gemm_kernel<<<ggemm, 256, 0, stream>>>(xbuf, 0, 128, d_out, 128, 256, flags, Wh, Wl, 0, H, N, 256);
    agg_kernel<<<gagg, 256, 0, stream>>>(H, csr, rp, dinv, b3, flags, d_out, 0, 256, 0, N);
    gemm_kernel<<<ggemm, 256, 0, stream>>>(xbuf, 0, 128, d_out, 128, 256, flags, Wh, Wl, 128, H, N, 256);
    agg_kernel<<<gagg, 256, 0, stream>>>(H, csr, rp, dinv, b3, flags, d_out, 128, 256, 0, N);
}

// Round 4
// 723.558 us; speedup vs baseline: 1.4962x; 1.4962x over previous
//
#include <hip/hip_runtime.h>

#define NN 100000
#define NE 800000
#define HID 256

typedef __attribute__((ext_vector_type(8))) short bf16x8;
typedef __attribute__((ext_vector_type(4))) float f32x4;
typedef __attribute__((ext_vector_type(4))) unsigned short us4;

__device__ __forceinline__ float bf2f(unsigned short u) {
    return __uint_as_float(((unsigned)u) << 16);
}
__device__ __forceinline__ unsigned short f2bf(float f) {
    unsigned u = __float_as_uint(f);
    u += 0x7fffu + ((u >> 16) & 1u);   // RNE
    return (unsigned short)(u >> 16);
}

// ---------- dtype probes: flags[0]=f32 world, flags[1]=edge is int64 ----------
__global__ void probe_kernel(const void* W1, const void* edge, int* flags) {
    __shared__ int s_f32, s_odd;
    if (threadIdx.x == 0) { s_f32 = 0; s_odd = 0; }
    __syncthreads();
    const unsigned short* wu = (const unsigned short*)W1;
    for (int i = threadIdx.x; i < 2048; i += 256) {
        float v = bf2f(wu[i]);
        if (!(fabsf(v) <= 1.0f)) atomicOr(&s_f32, 1);
    }
    const int* ei = (const int*)edge;
    for (int i = threadIdx.x; i < 512; i += 256) {
        if (ei[2 * i + 1] != 0) atomicOr(&s_odd, 1);
    }
    __syncthreads();
    if (threadIdx.x == 0) { flags[0] = s_f32; flags[1] = s_odd ? 0 : 1; }
}

__device__ __forceinline__ int get_edge(const void* edge, int e64, long long idx) {
    return e64 ? (int)((const long long*)edge)[idx] : ((const int*)edge)[idx];
}
__device__ __forceinline__ float get_f(const void* p, int f32, size_t idx) {
    return f32 ? ((const float*)p)[idx] : bf2f(((const unsigned short*)p)[idx]);
}

// ---------- CSR build ----------
__global__ void zero_kernel(int* deg, int n) {
    int i = blockIdx.x * 256 + threadIdx.x;
    if (i < n) deg[i] = 0;
}
__global__ void count_kernel(const void* __restrict__ edge, const int* __restrict__ flags,
                             int* __restrict__ deg, int e) {
    int i = blockIdx.x * 256 + threadIdx.x;
    if (i < e) atomicAdd(&deg[get_edge(edge, flags[1], (long long)NE + i)], 1);
}
__global__ void dinv_kernel(const int* __restrict__ deg, float* __restrict__ dinv, int n) {
    int i = blockIdx.x * 256 + threadIdx.x;
    if (i < n) dinv[i] = 1.0f / sqrtf((float)(deg[i] + 1));
}
__global__ void scanA_kernel(const int* __restrict__ deg, int* __restrict__ rp,
                             int* __restrict__ bsums, int n) {
    __shared__ int sd[256];
    int tid = threadIdx.x;
    int base = blockIdx.x * 1024 + tid * 4;
    int v[4]; int ts = 0;
    for (int j = 0; j < 4; ++j) { v[j] = (base + j < n) ? deg[base + j] : 0; ts += v[j]; }
    sd[tid] = ts;
    __syncthreads();
    for (int off = 1; off < 256; off <<= 1) {
        int t = (tid >= off) ? sd[tid - off] : 0;
        __syncthreads();
        sd[tid] += t;
        __syncthreads();
    }
    int run = sd[tid] - ts;
    for (int j = 0; j < 4; ++j) {
        if (base + j < n) rp[base + j] = run;
        run += v[j];
    }
    if (tid == 255) bsums[blockIdx.x] = sd[255];
}
__global__ void scanB_kernel(int* bsums, int nb) {
    __shared__ int sd[128];
    int tid = threadIdx.x;
    int v = (tid < nb) ? bsums[tid] : 0;
    sd[tid] = v;
    __syncthreads();
    for (int off = 1; off < 128; off <<= 1) {
        int t = (tid >= off) ? sd[tid - off] : 0;
        __syncthreads();
        sd[tid] += t;
        __syncthreads();
    }
    if (tid < nb) bsums[tid] = sd[tid] - v;
}
__global__ void scanC_kernel(int* __restrict__ rp, const int* __restrict__ bsums, int n) {
    int base = blockIdx.x * 1024 + threadIdx.x * 4;
    int off = bsums[blockIdx.x];
    for (int j = 0; j < 4; ++j)
        if (base + j < n) rp[base + j] += off;
}
// countdown fill (destroys deg; dinv already extracted)
__global__ void fill_kernel(const void* __restrict__ edge, const int* __restrict__ flags,
                            const int* __restrict__ rp, int* __restrict__ deg,
                            int* __restrict__ csr, int e) {
    int i = blockIdx.x * 256 + threadIdx.x;
    if (i >= e) return;
    int e64 = flags[1];
    int s = get_edge(edge, e64, i);
    int d = get_edge(edge, e64, (long long)NE + i);
    int slot = atomicAdd(&deg[d], -1) - 1;
    csr[rp[d] + slot] = s;
}

// ---------- cast x -> bf16 plane ----------
__global__ void cast_kernel(const void* __restrict__ x, const int* __restrict__ flags,
                            unsigned short* __restrict__ xb, int n4) {
    int i = blockIdx.x * 256 + threadIdx.x;
    if (i >= n4) return;
    size_t o = (size_t)i * 4;
    us4 out;
    if (flags[0]) {
        float4 v = *(const float4*)((const float*)x + o);
        out[0] = f2bf(v.x); out[1] = f2bf(v.y); out[2] = f2bf(v.z); out[3] = f2bf(v.w);
    } else {
        out = *(const us4*)((const unsigned short*)x + o);
    }
    *(us4*)(xb + o) = out;
}

// ---------- weight transpose + hi/lo split: W[k,256] -> Wh/Wl[n,K] ----------
__global__ void wsplit_kernel(const void* __restrict__ W, const int* __restrict__ flags,
                              unsigned short* __restrict__ Wh, unsigned short* __restrict__ Wl,
                              int K) {
    int k = blockIdx.x, n = threadIdx.x;
    float v = get_f(W, flags[0], (size_t)k * 256 + n);
    unsigned short h = f2bf(v);
    Wh[n * K + k] = h;
    Wl[n * K + k] = f2bf(v - bf2f(h));
}

// ---------- pre-aggregation: out[i] = dinv_i * sum_j dinv_j act[j] + dinv_i^2 act[i] ----------
// one wave per node, CPL cols/lane (width = 64*CPL), bf16 in -> bf16 out, f32 accum
template <int CPL>
__global__ __launch_bounds__(256) void agg_kernel(
    const unsigned short* __restrict__ act, const int* __restrict__ csr,
    const int* __restrict__ rp, const float* __restrict__ dinv,
    unsigned short* __restrict__ out, int n) {
    const int W = CPL * 64;
    int wave = threadIdx.x >> 6;
    int lane = threadIdx.x & 63;
    int node = blockIdx.x * 4 + wave;
    if (node >= n) return;
    int c = lane * CPL;

    float acc[CPL];
    for (int j = 0; j < CPL; ++j) acc[j] = 0.f;

    int beg = rp[node];
    int end = (node == n - 1) ? NE : rp[node + 1];

    int i = beg;
    for (; i + 1 < end; i += 2) {
        int s0 = __builtin_amdgcn_readfirstlane(csr[i]);
        int s1 = __builtin_amdgcn_readfirstlane(csr[i + 1]);
        float w0 = dinv[s0], w1 = dinv[s1];
        if (CPL == 4) {
            us4 h0 = *(const us4*)(act + (size_t)s0 * W + c);
            us4 h1 = *(const us4*)(act + (size_t)s1 * W + c);
            for (int j = 0; j < 4; ++j) acc[j] += bf2f(h0[j]) * w0 + bf2f(h1[j]) * w1;
        } else {
            ushort2 h0 = *(const ushort2*)(act + (size_t)s0 * W + c);
            ushort2 h1 = *(const ushort2*)(act + (size_t)s1 * W + c);
            acc[0] += bf2f(h0.x) * w0 + bf2f(h1.x) * w1;
            acc[1] += bf2f(h0.y) * w0 + bf2f(h1.y) * w1;
        }
    }
    if (i < end) {
        int s0 = __builtin_amdgcn_readfirstlane(csr[i]);
        float w0 = dinv[s0];
        if (CPL == 4) {
            us4 h0 = *(const us4*)(act + (size_t)s0 * W + c);
            for (int j = 0; j < 4; ++j) acc[j] += bf2f(h0[j]) * w0;
        } else {
            ushort2 h0 = *(const ushort2*)(act + (size_t)s0 * W + c);
            acc[0] += bf2f(h0.x) * w0;
            acc[1] += bf2f(h0.y) * w0;
        }
    }

    float dn = dinv[node];
    if (CPL == 4) {
        us4 hs = *(const us4*)(act + (size_t)node * W + c);
        us4 ov;
        for (int j = 0; j < 4; ++j)
            ov[j] = f2bf(acc[j] * dn + bf2f(hs[j]) * (dn * dn));
        *(us4*)(out + (size_t)node * W + c) = ov;
    } else {
        ushort2 hs = *(const ushort2*)(act + (size_t)node * W + c);
        ushort2 ov;
        ov.x = f2bf(acc[0] * dn + bf2f(hs.x) * (dn * dn));
        ov.y = f2bf(acc[1] * dn + bf2f(hs.y) * (dn * dn));
        *(ushort2*)(out + (size_t)node * W + c) = ov;
    }
}

// ---------- GEMM: out[:,col0:col0+128] = A[M,K] @ (Wh+Wl)[:,col0:col0+128] + b (relu?) ----------
#define BM 128
#define BK 32
#define LDA 40

__global__ __launch_bounds__(256) void gemm_kernel(
    const unsigned short* __restrict__ A, int K,
    const unsigned short* __restrict__ Wh, const unsigned short* __restrict__ Wl,
    int col0, const void* __restrict__ bias, const int* __restrict__ flags,
    int relu, int is_final,
    unsigned short* __restrict__ outb, float* __restrict__ outf, int M) {
    __shared__ __align__(16) short Ah[BM * LDA];
    __shared__ __align__(16) short Bh[128 * LDA];
    __shared__ __align__(16) short Bl[128 * LDA];

    int tid = threadIdx.x;
    int lane = tid & 63;
    int wave = tid >> 6;
    int wm = wave >> 1, wn = wave & 1;
    int row0 = blockIdx.x * BM;
    int f32 = flags[0];

    f32x4 acc[4][4];
    for (int mt = 0; mt < 4; ++mt)
        for (int nt = 0; nt < 4; ++nt)
            acc[mt][nt] = (f32x4){0.f, 0.f, 0.f, 0.f};

    for (int k0 = 0; k0 < K; k0 += BK) {
        for (int s = tid; s < 512; s += 256) {
            int r = s >> 2, q = s & 3;
            int gr = row0 + r;
            uint4 v = make_uint4(0, 0, 0, 0);
            if (gr < M)
                v = *(const uint4*)(A + (size_t)gr * K + k0 + q * 8);
            *(uint4*)&Ah[r * LDA + q * 8] = v;
        }
        for (int s = tid; s < 512; s += 256) {
            int r = s >> 2, q = s & 3;
            size_t gi = (size_t)(col0 + r) * K + k0 + q * 8;
            int lds = r * LDA + q * 8;
            *(uint4*)&Bh[lds] = *(const uint4*)(Wh + gi);
            *(uint4*)&Bl[lds] = *(const uint4*)(Wl + gi);
        }
        __syncthreads();

        int kq = (lane >> 4) * 8;
        bf16x8 af[4], bh[4], bl[4];
        for (int t = 0; t < 4; ++t) {
            int ar = (wm * 64 + t * 16 + (lane & 15)) * LDA + kq;
            int br = (wn * 64 + t * 16 + (lane & 15)) * LDA + kq;
            af[t] = *(const bf16x8*)&Ah[ar];
            bh[t] = *(const bf16x8*)&Bh[br];
            bl[t] = *(const bf16x8*)&Bl[br];
        }
        for (int mt = 0; mt < 4; ++mt)
            for (int nt = 0; nt < 4; ++nt) {
                acc[mt][nt] = __builtin_amdgcn_mfma_f32_16x16x32_bf16(af[mt], bh[nt], acc[mt][nt], 0, 0, 0);
                acc[mt][nt] = __builtin_amdgcn_mfma_f32_16x16x32_bf16(af[mt], bl[nt], acc[mt][nt], 0, 0, 0);
            }
        __syncthreads();
    }

    // C/D layout: col=lane&15 (+16*nt), row=(lane>>4)*4+i
    int wf32 = is_final && f32;
    for (int mt = 0; mt < 4; ++mt)
        for (int nt = 0; nt < 4; ++nt) {
            int col = col0 + wn * 64 + nt * 16 + (lane & 15);
            float bv = get_f(bias, f32, (size_t)col);
            int rbase = row0 + wm * 64 + mt * 16 + ((lane >> 4) << 2);
            for (int i = 0; i < 4; ++i) {
                int r = rbase + i;
                if (r < M) {
                    float v = acc[mt][nt][i] + bv;
                    if (relu) v = fmaxf(v, 0.f);
                    if (wf32) outf[(size_t)r * HID + col] = v;
                    else outb[(size_t)r * HID + col] = f2bf(v);
                }
            }
        }
}

// ---------- launch ----------
extern "C" void kernel_launch(void* const* d_in, const int* in_sizes, int n_in,
                              void* d_out, int out_size, void* d_ws, size_t ws_size,
                              hipStream_t stream) {
    const void* x    = d_in[0];
    const void* edge = d_in[1];
    const void* W1   = d_in[2];
    const void* b1   = d_in[3];
    const void* W2   = d_in[4];
    const void* b2   = d_in[5];
    const void* W3   = d_in[6];
    const void* b3   = d_in[7];

    const int N = NN, E = NE;

    char* w = (char*)d_ws;
    auto carve = [&](size_t bytes) -> void* {
        void* p = (void*)w;
        w += (bytes + 255) & ~(size_t)255;
        return p;
    };
    int*   flags = (int*)carve(256);
    int*   deg   = (int*)carve((size_t)N * 4);
    float* dinv  = (float*)carve((size_t)N * 4);
    int*   rp    = (int*)carve((size_t)N * 4);
    int*   bsums = (int*)carve(512);
    int*   csr   = (int*)carve((size_t)E * 4);
    unsigned short* Wh = (unsigned short*)carve((size_t)256 * 256 * 2);
    unsigned short* Wl = (unsigned short*)carve((size_t)256 * 256 * 2);
    unsigned short* Agg = (unsigned short*)carve((size_t)N * HID * 2);  // 51.2 MB; total ~55.9 MB

    // d_out doubles as scratch until the final GEMM overwrites it:
    //   xb  = bf16 x [N,128] at d_out[0:25.6MB]  (consumed by L1 agg)
    //   act = bf16 [N,256]   at d_out[0:51.2MB]  (layer l output, consumed by layer l+1 agg)
    unsigned short* xb  = (unsigned short*)d_out;
    unsigned short* act = (unsigned short*)d_out;

    int gN = (N + 255) / 256;
    int gE = (E + 255) / 256;
    int nb = (N + 1023) / 1024;
    dim3 ggemm(782);
    int gagg = (N + 3) / 4;

    probe_kernel<<<1, 256, 0, stream>>>(W1, edge, flags);
    zero_kernel<<<gN, 256, 0, stream>>>(deg, N);
    count_kernel<<<gE, 256, 0, stream>>>(edge, flags, deg, E);
    dinv_kernel<<<gN, 256, 0, stream>>>(deg, dinv, N);
    scanA_kernel<<<nb, 256, 0, stream>>>(deg, rp, bsums, N);
    scanB_kernel<<<1, 128, 0, stream>>>(bsums, nb);
    scanC_kernel<<<nb, 256, 0, stream>>>(rp, bsums, N);
    fill_kernel<<<gE, 256, 0, stream>>>(edge, flags, rp, deg, csr, E);
    cast_kernel<<<(N * 128 / 4 + 255) / 256, 256, 0, stream>>>(x, flags, xb, N * 128 / 4);

    // ---- layer 1 (K=128) ----
    wsplit_kernel<<<128, 256, 0, stream>>>(W1, flags, Wh, Wl, 128);
    agg_kernel<2><<<gagg, 256, 0, stream>>>(xb, csr, rp, dinv, Agg, N);
    gemm_kernel<<<ggemm, 256, 0, stream>>>(Agg, 128, Wh, Wl, 0,   b1, flags, 1, 0, act, nullptr, N);
    gemm_kernel<<<ggemm, 256, 0, stream>>>(Agg, 128, Wh, Wl, 128, b1, flags, 1, 0, act, nullptr, N);

    // ---- layer 2 (K=256) ----
    wsplit_kernel<<<256, 256, 0, stream>>>(W2, flags, Wh, Wl, 256);
    agg_kernel<4><<<gagg, 256, 0, stream>>>(act, csr, rp, dinv, Agg, N);
    gemm_kernel<<<ggemm, 256, 0, stream>>>(Agg, 256, Wh, Wl, 0,   b2, flags, 1, 0, act, nullptr, N);
    gemm_kernel<<<ggemm, 256, 0, stream>>>(Agg, 256, Wh, Wl, 128, b2, flags, 1, 0, act, nullptr, N);

    // ---- layer 3 (K=256, final) ----
    wsplit_kernel<<<256, 256, 0, stream>>>(W3, flags, Wh, Wl, 256);
    agg_kernel<4><<<gagg, 256, 0, stream>>>(act, csr, rp, dinv, Agg, N);
    gemm_kernel<<<ggemm, 256, 0, stream>>>(Agg, 256, Wh, Wl, 0,   b3, flags, 0, 1,
                                           (unsigned short*)d_out, (float*)d_out, N);
    gemm_kernel<<<ggemm, 256, 0, stream>>>(Agg, 256, Wh, Wl, 128, b3, flags, 0, 1,
                                           (unsigned short*)d_out, (float*)d_out, N);
}